// Round 5
// baseline (427.227 us; speedup 1.0000x reference)
//
#include <hip/hip_runtime.h>
#include <hip/hip_bf16.h>

// Problem constants
#define HH 256
#define WW 256
#define CCH 1024
#define PP 1024   // 32*32 patches per image

using f32x4 = __attribute__((ext_vector_type(4))) float;
using short8 = __attribute__((ext_vector_type(8))) short;

// ---------------------------------------------------------------------------
// K1: patch average pool.  Block per (b,c) plane (2048 blocks, 4 waves, no
// LDS/barriers).  Wave w handles patch-rows w, w+4, ..., w+28; per slab the
// wave reads 8 full 256-col rows (f32x4/lane), pair-reduces via shfl_xor(1),
// and even lanes store 32 CONSECUTIVE f32s (one 128B line per wave) into
// y[b][c][p].  Line-granular writes only — no cross-block false sharing
// (R4's 2B cross-XCD scatter diverged under graph replay).
// ---------------------------------------------------------------------------
__global__ __launch_bounds__(256) void pool_kernel(const float* __restrict__ x,
                                                   float* __restrict__ y) {
    int bc   = blockIdx.x;               // b*1024 + c
    int wid  = threadIdx.x >> 6;         // 0..3
    int lane = threadIdx.x & 63;
    const float* xp = x + (size_t)bc * (HH * WW) + lane * 4;
    float* yp = y + (size_t)bc * PP;
#pragma unroll
    for (int s = 0; s < 8; ++s) {
        int ph = wid + s * 4;            // patch row 0..31
        const float* slab = xp + (size_t)ph * 8 * WW;
        float acc = 0.f;
#pragma unroll
        for (int r = 0; r < 8; ++r) {
            f32x4 v = __builtin_nontemporal_load((const f32x4*)(slab + (size_t)r * WW));
            acc += v.x + v.y + v.z + v.w;
        }
        acc += __shfl_xor(acc, 1);
        if ((lane & 1) == 0)
            yp[ph * 32 + (lane >> 1)] = acc * (1.f / 64.f);
    }
}

// ---------------------------------------------------------------------------
// K2: conv weight f32 [co][ci][3] -> bf16 wT[tap][co][ci] (3 planes of 1M),
// plus zero the pad rows of yT (p = -1 and p = 1024) in the first 2048 threads.
// ---------------------------------------------------------------------------
__global__ __launch_bounds__(256) void wconv_pad_kernel(const float* __restrict__ w,
                                                        __hip_bfloat16* __restrict__ wT,
                                                        __hip_bfloat16* __restrict__ yT) {
    int tid = blockIdx.x * 256 + threadIdx.x;   // co*1024 + ci
    const float* p = w + (size_t)tid * 3;
    float a = p[0], b = p[1], c = p[2];
    wT[tid]               = __float2bfloat16(a);
    wT[(1u << 20) + tid]  = __float2bfloat16(b);
    wT[(2u << 20) + tid]  = __float2bfloat16(c);
    if (tid < 2 * CCH) {
        int bb = tid >> 10, cc = tid & 1023;
        __hip_bfloat16 z = __float2bfloat16(0.f);
        __hip_bfloat16* base = yT + (size_t)bb * (PP + 2) * CCH;
        base[cc] = z;
        base[(size_t)(PP + 1) * CCH + cc] = z;
    }
}

// ---------------------------------------------------------------------------
// K3: transpose+convert y[b][c][p] f32 -> yT[b][1+p][c] bf16 (32x32 LDS tiles)
// Writes are 64B-contiguous per row segment (line-granular, replay-safe).
// ---------------------------------------------------------------------------
__global__ __launch_bounds__(256) void transpose_kernel(const float* __restrict__ y,
                                                        __hip_bfloat16* __restrict__ yT) {
    int b  = blockIdx.z;
    int c0 = blockIdx.x * 32;
    int p0 = blockIdx.y * 32;
    __shared__ float tile[32][33];
    int tx = threadIdx.x, ty = threadIdx.y;    // 32 x 8
    const float* yb = y + (size_t)b * CCH * PP;
#pragma unroll
    for (int rr = 0; rr < 4; ++rr)
        tile[ty + rr * 8][tx] = yb[(size_t)(c0 + ty + rr * 8) * PP + p0 + tx];
    __syncthreads();
    __hip_bfloat16* yTb = yT + (size_t)b * (PP + 2) * CCH;
#pragma unroll
    for (int rr = 0; rr < 4; ++rr)
        yTb[(size_t)(1 + p0 + ty + rr * 8) * CCH + c0 + tx] =
            __float2bfloat16(tile[tx][ty + rr * 8]);
}

// ---------------------------------------------------------------------------
// K4: conv-as-GEMM, bf16 MFMA.  Block = 64(co) x 64(p) tile, 512 threads =
// 8 waves (4 co-groups x 2 p-groups); wave tile 16x32.  Grid 16x16x2 = 512
// blocks -> 4096 waves -> 4 waves/SIMD.
// ---------------------------------------------------------------------------
__global__ __launch_bounds__(512) void conv_gemm_kernel(
        const __hip_bfloat16* __restrict__ wT,
        const __hip_bfloat16* __restrict__ yT,
        float* __restrict__ gate) {
    int lane = threadIdx.x & 63;
    int wid  = threadIdx.x >> 6;                // 0..7
    int wp  = wid & 1, wco = wid >> 1;
    int l15 = lane & 15, lhi = lane >> 4;       // lhi: 0..3
    int co_base = blockIdx.x * 64 + wco * 16;
    int p_base  = blockIdx.y * 64 + wp * 32;
    int b = blockIdx.z;
    const __hip_bfloat16* yTb = yT + (size_t)b * (PP + 2) * CCH;

    f32x4 acc[2] = {};
#pragma unroll
    for (int tap = 0; tap < 3; ++tap) {
        const __hip_bfloat16* Ap = wT + (size_t)tap * (1u << 20)
                                 + (size_t)(co_base + l15) * CCH + lhi * 8;
        const __hip_bfloat16* Bp = yTb + (size_t)(p_base + l15 + tap) * CCH + lhi * 8;
        for (int ci0 = 0; ci0 < CCH; ci0 += 32) {
            short8 a0 = *(const short8*)(Ap + ci0);
            short8 b0 = *(const short8*)(Bp + ci0);
            short8 b1 = *(const short8*)(Bp + ci0 + 16 * CCH);
            acc[0] = __builtin_amdgcn_mfma_f32_16x16x32_bf16(a0, b0, acc[0], 0, 0, 0);
            acc[1] = __builtin_amdgcn_mfma_f32_16x16x32_bf16(a0, b1, acc[1], 0, 0, 0);
        }
    }
    // Epilogue: sigmoid, store gate f32.  C/D layout: col = lane&15,
    // row = (lane>>4)*4 + reg  [measured m89/m91].
    float* gb = gate + (size_t)b * CCH * PP;
#pragma unroll
    for (int j16 = 0; j16 < 2; ++j16) {
        int col  = p_base + j16 * 16 + l15;
        int row0 = co_base + lhi * 4;
#pragma unroll
        for (int r = 0; r < 4; ++r) {
            float v = acc[j16][r];
            gb[(size_t)(row0 + r) * PP + col] = 1.f / (1.f + __expf(-v));
        }
    }
}

// ---------------------------------------------------------------------------
// K5: out = x * gate.  Block per (b,c) plane; gate row (4 KB) in LDS; wave
// covers one full 256-col row per iteration (coalesced f32x4, NT in+out).
// ---------------------------------------------------------------------------
__global__ __launch_bounds__(256) void apply_kernel(const float* __restrict__ x,
                                                    const float* __restrict__ gate,
                                                    float* __restrict__ out) {
    int bc = blockIdx.x;                 // b*1024 + c
    const float* xp = x   + (size_t)bc * (HH * WW);
    float*       op = out + (size_t)bc * (HH * WW);
    __shared__ float g[PP];
    int t = threadIdx.x;
    ((f32x4*)g)[t] = ((const f32x4*)(gate + (size_t)bc * PP))[t];
    __syncthreads();
    int col4 = t & 63;                   // lane (wave covers full row)
    int r    = t >> 6;                   // wave id = row offset
    int pc   = col4 >> 1;
#pragma unroll 4
    for (int it = 0; it < 64; ++it) {
        int row = it * 4 + r;
        float gg = g[(row >> 3) * 32 + pc];
        size_t off = (size_t)row * 64 + col4;     // in f32x4 units
        f32x4 v = __builtin_nontemporal_load((const f32x4*)xp + off);
        v *= gg;
        __builtin_nontemporal_store(v, (f32x4*)op + off);
    }
}

extern "C" void kernel_launch(void* const* d_in, const int* in_sizes, int n_in,
                              void* d_out, int out_size, void* d_ws, size_t ws_size,
                              hipStream_t stream) {
    const float* x = (const float*)d_in[0];       // [2,1024,256,256] f32
    const float* w = (const float*)d_in[1];       // [1024,1024,3] f32
    float* out = (float*)d_out;                   // [2,1024,256,256] f32

    // Workspace layout (256-aligned):
    //   y    f32  [2][1024][1024]   8,388,608 B @ 0
    //   yT   bf16 [2][1026][1024]   4,202,496 B @  8,388,608
    //   wT   bf16 [3][1024][1024]   6,291,456 B @ 12,591,104
    //   gate f32  [2][1024][1024]   8,388,608 B @ 18,882,560   (tot ~26 MiB)
    char* ws = (char*)d_ws;
    float*          y    = (float*)(ws);
    __hip_bfloat16* yT   = (__hip_bfloat16*)(ws + 8388608);
    __hip_bfloat16* wT   = (__hip_bfloat16*)(ws + 12591104);
    float*          gate = (float*)(ws + 18882560);

    hipLaunchKernelGGL(pool_kernel,      dim3(2048),      dim3(256),   0, stream, x, y);
    hipLaunchKernelGGL(wconv_pad_kernel, dim3(4096),      dim3(256),   0, stream, w, wT, yT);
    hipLaunchKernelGGL(transpose_kernel, dim3(32, 32, 2), dim3(32, 8), 0, stream, y, yT);
    hipLaunchKernelGGL(conv_gemm_kernel, dim3(16, 16, 2), dim3(512),   0, stream, wT, yT, gate);
    hipLaunchKernelGGL(apply_kernel,     dim3(2048),      dim3(256),   0, stream, x, gate, out);
}